// Round 5
// baseline (508.342 us; speedup 1.0000x reference)
//
#include <hip/hip_runtime.h>
#include <hip/hip_bf16.h>

// DecoderBlock: h_t = tanh(x_t @ U + h_{t-1} @ V + b)
// BZ=256, SEQ=512, IN=HID=256. fp32 in/out.
//
// Single fused kernel. 1 WG per batch row. THIS ROUND: 256 thr (4 waves,
// 1 wave/SIMD) instead of 512. Per-SIMD MFMA count is unchanged (32/step,
// the structural floor), but: h-broadcast LDS reads halve (32 vs 64 b128
// per CU-step), barrier syncs 4 waves not 8, and a quad->n-tile mapping
// (lane l owns column 64w+l) gives a 1-column VALU tail, an all-lane
// conflict-free ds_write_b16 h-update and perfectly coalesced h stores.
// U and V both persist as fp16 B-fragments in registers (256 VGPR; at
// 1 wave/SIMD up to 512 VGPR is spill-free).

#define SEQn   512
#define HIDn   256
#define CHUNK  64
#define NCHUNK 8

typedef __attribute__((ext_vector_type(4))) float    floatx4;
typedef __attribute__((ext_vector_type(4))) _Float16 half4;
typedef __attribute__((ext_vector_type(8))) _Float16 half8;

// LDS-only barrier: drain LDS ops, then sync. Global ops stay in flight.
#define LDS_BARRIER() asm volatile("s_waitcnt lgkmcnt(0)\n\ts_barrier" ::: "memory")

__global__ __launch_bounds__(256, 1)
void rnn_fused(const float* __restrict__ enc, const float* __restrict__ x,
               const float* __restrict__ U,   const float* __restrict__ V,
               const float* __restrict__ bias, float* __restrict__ out)
{
    __shared__ _Float16 xbf[CHUNK][HIDn];     // 32 KB; 16B-group m at slot m^(row&7)
    __shared__ float    xu[CHUNK][HIDn + 1];  // 65.8 KB
    __shared__ _Float16 hbuf[2][HIDn];        // 1 KB ping-pong

    const int tid = threadIdx.x;
    const int w   = tid >> 6;        // wave 0..3
    const int l   = tid & 63;
    const int lr  = l & 15;
    const int q   = l >> 4;
    const int b   = blockIdx.x;
    const int cw  = 64 * w;          // wave column base; lane owns col cw+l

    // ---- persistent U,V fp16 B-fragments: [nt][c][j] = M[32c+8q+j][cw+16nt+lr]
    // 2 matrices x 32 frags x 4 VGPR = 256 VGPRs.
    half8 uf[4][8], vf[4][8];
    #pragma unroll
    for (int c = 0; c < 8; c++) {
        const float* up = U + (size_t)(32 * c + 8 * q) * HIDn + cw + lr;
        const float* vp = V + (size_t)(32 * c + 8 * q) * HIDn + cw + lr;
        #pragma unroll
        for (int nt = 0; nt < 4; nt++) {
            half8 tu, tv;
            #pragma unroll
            for (int j = 0; j < 8; j++) {
                tu[j] = (_Float16)up[(size_t)j * HIDn + 16 * nt];
                tv[j] = (_Float16)vp[(size_t)j * HIDn + 16 * nt];
            }
            uf[nt][c] = tu;
            vf[nt][c] = tv;
        }
    }

    float bv[4];
    #pragma unroll
    for (int nt = 0; nt < 4; nt++) bv[nt] = bias[cw + 16 * nt + lr];

    // ---- h0 init + encoder passthrough (256 threads = 256 cols) ----
    {
        float h0 = enc[(size_t)b * HIDn + tid];
        out[(size_t)b * HIDn + tid] = h0;
        hbuf[0][tid] = (_Float16)h0;
    }

    const float* xb = x + (size_t)b * SEQn * HIDn;
    float* outDec   = out + (size_t)65536 + (size_t)b * SEQn * HIDn;

    // staging map: thread covers row tid>>2, float4 at col 16*i + 4*(tid&3)
    const int srow = tid >> 2;
    const int sc4  = tid & 3;

    const floatx4 zf = {0.f, 0.f, 0.f, 0.f};

    int p = 0;
    for (int g = 0; g < NCHUNK; g++) {
        // ================= phase A1: stage x chunk as fp16 =================
        const float* xs = xb + (size_t)(g * CHUNK + srow) * HIDn + 4 * sc4;
        float4 xv[16];
        #pragma unroll
        for (int i = 0; i < 16; i++)
            xv[i] = *(const float4*)(xs + 16 * i);
        #pragma unroll
        for (int i = 0; i < 16; i++) {
            half4 t;
            t[0] = (_Float16)xv[i].x; t[1] = (_Float16)xv[i].y;
            t[2] = (_Float16)xv[i].z; t[3] = (_Float16)xv[i].w;
            // col16B-group m = 2i + (sc4>>1); half-of-group = sc4&1
            int grp = (2 * i + (sc4 >> 1)) ^ (srow & 7);
            *(half4*)&xbf[srow][grp * 8 + 4 * (sc4 & 1)] = t;
        }
        LDS_BARRIER();

        // ====== phase A2: GEMM  xu[step][col] = x_chunk @ U + bias ======
        // wave w: 4 n-tiles (cols cw..cw+64), 4 m-tiles, K=256.
        {
            floatx4 ga[4][4];   // [mt][nt]
            #pragma unroll
            for (int c = 0; c < 8; c++) {
                half8 am[4];
                #pragma unroll
                for (int mt = 0; mt < 4; mt++) {
                    int row = 16 * mt + lr;
                    int grp = (4 * c + q) ^ (row & 7);
                    am[mt] = *(const half8*)&xbf[row][grp * 8];
                }
                #pragma unroll
                for (int mt = 0; mt < 4; mt++)
                    #pragma unroll
                    for (int nt = 0; nt < 4; nt++)
                        ga[mt][nt] = __builtin_amdgcn_mfma_f32_16x16x32_f16(
                            am[mt], uf[nt][c], c ? ga[mt][nt] : zf, 0, 0, 0);
            }
            #pragma unroll
            for (int mt = 0; mt < 4; mt++)
                #pragma unroll
                for (int nt = 0; nt < 4; nt++)
                    #pragma unroll
                    for (int r = 0; r < 4; r++)
                        xu[16 * mt + 4 * q + r][cw + 16 * nt + lr] =
                            ga[mt][nt][r] + bv[nt];
        }
        LDS_BARRIER();

        // ================= phase B: 64 recurrence steps =================
        for (int tt = 0; tt < CHUNK; tt++) {
            // xu for this lane's column — independent of h, off critical path
            float xuv = xu[tt][cw + l];

            // A-frags: h broadcast to all 16 m-rows (quad-selected 16B reads)
            half8 af[8];
            #pragma unroll
            for (int c = 0; c < 8; c++)
                af[c] = *(const half8*)&hbuf[p][32 * c + 8 * q];

            // 32 MFMAs: 4 n-tiles x 8 k-chunks, 2 chains of depth 4 per tile
            floatx4 acc[4][2];
            #pragma unroll
            for (int c = 0; c < 8; c++) {
                const int ch = c & 1;
                #pragma unroll
                for (int nt = 0; nt < 4; nt++)
                    acc[nt][ch] = __builtin_amdgcn_mfma_f32_16x16x32_f16(
                        af[c], vf[nt][c], (c < 2) ? zf : acc[nt][ch], 0, 0, 0);
            }

            // lane owns col cw + l  (= cw + 16q + lr): select n-tile q
            float a0 = acc[0][0][0] + acc[0][1][0];
            float a1 = acc[1][0][0] + acc[1][1][0];
            float a2 = acc[2][0][0] + acc[2][1][0];
            float a3 = acc[3][0][0] + acc[3][1][0];
            float t01 = (q & 1) ? a1 : a0;
            float t23 = (q & 1) ? a3 : a2;
            float s   = ((q & 2) ? t23 : t01) + xuv;

            float e  = __expf(2.f * s);
            float hv = 1.f - __fdividef(2.f, e + 1.f);

            hbuf[p ^ 1][cw + l] = (_Float16)hv;                       // all lanes, 2-way free
            outDec[(size_t)(g * CHUNK + tt) * HIDn + cw + l] = hv;    // coalesced, fire-and-forget
            p ^= 1;
            LDS_BARRIER();   // globals stay in flight
        }
    }
}

extern "C" void kernel_launch(void* const* d_in, const int* in_sizes, int n_in,
                              void* d_out, int out_size, void* d_ws, size_t ws_size,
                              hipStream_t stream) {
    const float* enc  = (const float*)d_in[0];   // [256,256]
    const float* x    = (const float*)d_in[1];   // [256,512,256]
    const float* U    = (const float*)d_in[2];   // [256,256]
    const float* V    = (const float*)d_in[3];   // [256,256]
    const float* bias = (const float*)d_in[4];   // [256]
    float* out = (float*)d_out;                  // 65536 + 33554432 floats

    rnn_fused<<<256, 256, 0, stream>>>(enc, x, U, V, bias, out);
}